// Round 3
// baseline (140.510 us; speedup 1.0000x reference)
//
#include <hip/hip_runtime.h>
#include <math.h>

// B=4, C=64, H=W=128, OUTC=64, KS=3, taps N=9, K = 9*64 = 576.
// ws layout (bytes):
//   x_t  bf16 [4][128][128][64]  @ 0         (8 MB)   NHWC
//   cwt  bf16 [64][576]          @ 8388608   (72 KB)  cwt[o][n*64+c] = conv_w[o][c][n]
//   pwt  bf16 [32][576]          @ 8462336   (36 KB)  pwt[n'][n*64+c] = p_w[n'][c][n], rows 18..31 = 0
#define CWT_OFF 8388608
#define PWT_OFF 8462336

typedef __attribute__((ext_vector_type(8))) short short8;
typedef __attribute__((ext_vector_type(8))) unsigned short ushort8;
typedef __attribute__((ext_vector_type(4))) float f32x4;

__device__ inline float bf2f(unsigned short u) {
    union { unsigned int i; float f; } c; c.i = ((unsigned int)u) << 16; return c.f;
}
__device__ inline unsigned short f2bf(float f) {
    union { float f; unsigned int i; } c; c.f = f;
    return (unsigned short)((c.i + 0x7FFFu + ((c.i >> 16) & 1u)) >> 16);
}

// ---------------- prep: x NCHW f32 -> NHWC bf16 ----------------
__global__ __launch_bounds__(256) void k_prep_x(const float* __restrict__ x,
                                                unsigned int* __restrict__ x_t_u32) {
    __shared__ float t[64][129];
    int b = blockIdx.x >> 7;
    int i = blockIdx.x & 127;
    for (int idx = threadIdx.x; idx < 64 * 128; idx += 256) {
        int c = idx >> 7, j = idx & 127;
        t[c][j] = x[(((size_t)(b * 64 + c) * 128 + i) << 7) + j];
    }
    __syncthreads();
    unsigned int* dst = x_t_u32 + ((size_t)(b * 128 + i)) * 128 * 32;  // 32 u32 per pixel
    for (int idx2 = threadIdx.x; idx2 < 4096; idx2 += 256) {
        int j = idx2 >> 5, c2 = idx2 & 31;
        unsigned int lo = f2bf(t[2 * c2][j]);
        unsigned int hi = f2bf(t[2 * c2 + 1][j]);
        dst[idx2] = lo | (hi << 16);
    }
}

// ---------------- prep: weights -> bf16 transposed ----------------
__global__ __launch_bounds__(256) void k_prep_w(const float* __restrict__ conv_w,
                                                const float* __restrict__ p_w,
                                                unsigned short* __restrict__ cwt,
                                                unsigned short* __restrict__ pwt) {
    int tid = blockIdx.x * 256 + threadIdx.x;
    if (tid < 36864) {  // cwt[o*576 + n*64 + c] = conv_w[(o*64+c)*9 + n]
        int o = tid / 576, k = tid - o * 576;
        int n = k >> 6, c = k & 63;
        cwt[tid] = f2bf(conv_w[(o * 64 + c) * 9 + n]);
    } else if (tid < 36864 + 18432) {  // pwt[np*576 + n*64 + c]
        int t = tid - 36864;
        int np = t / 576, k = t - np * 576;
        int n = k >> 6, c = k & 63;
        pwt[t] = (np < 18) ? f2bf(p_w[(np * 64 + c) * 9 + n]) : (unsigned short)0;
    }
}

// ---------------- fused: offset-conv MFMA + geometry + bilinear + main MFMA ----------------
// Block = 64 pixels (b, i, j0..j0+63). 8 waves (512 thr):
//   wave wv -> pixel group pg = wv&3 (16 px), output half nbh = wv>>2.
// Phase 1: wave (pg, nbh) computes offset channels nbh*16..+15 for its 16 px.
// Phase 3: wave (pg, nbh) computes outputs nbh*32..+31 for its 16 px.
// MFMA 16x16x32 bf16. A frag: m=lane&15, k=8*(lane>>4)+e. B frag: n=lane&15, same k.
// D: n=lane&15, m=4*(lane>>4)+reg.
__global__ __launch_bounds__(512, 4) void k_fused(const unsigned short* __restrict__ x_t,
                                                  const unsigned short* __restrict__ cwt,
                                                  const unsigned short* __restrict__ pwt,
                                                  const float* __restrict__ p_b,
                                                  const float* __restrict__ conv_b,
                                                  float* __restrict__ out) {
    __shared__ float S[5760];
    float* offs = S;                       // [64][18] f32
    int* igeom = (int*)(S + 1152);         // [9][4][64]
    float* wgeom = S + 3456;               // [9][4][64]
    float* ep = S + 1152;                  // [64][65] epilogue (reuses geom region)

    int bid = blockIdx.x;
    int b = bid >> 8;
    int i = (bid >> 1) & 127;
    int j0 = (bid & 1) << 6;

    int tid = threadIdx.x;
    int wv = tid >> 6;
    int lane = tid & 63;
    int r15 = lane & 15;
    int g = lane >> 4;
    int c0 = g << 3;          // 8*(lane>>4)
    int pg = wv & 3;
    int nbh = wv >> 2;
    int pl = pg * 16 + r15;   // this lane's A-row pixel (within block)

    // ---- phase 1: offset conv via MFMA, A direct from x_t (branch-free) ----
    f32x4 aco = (f32x4)0.f;
    for (int n = 0; n < 9; ++n) {
        int du = n / 3 - 1, dv = n % 3 - 1;
        int row = i + du;
        int col = j0 + pl + dv;
        bool valid = ((unsigned)row < 128u) && ((unsigned)col < 128u);
        int rowc = valid ? row : 0;
        int colc = valid ? col : 0;
        const unsigned short* ap = x_t + (((size_t)((b * 128 + rowc) * 128 + colc)) << 6);
        ushort8 v0 = *(const ushort8*)(ap + c0);
        ushort8 v1 = *(const ushort8*)(ap + c0 + 32);
        if (!valid) { v0 = (ushort8)(unsigned short)0; v1 = (ushort8)(unsigned short)0; }
        const unsigned short* bp = pwt + (nbh * 16 + r15) * 576 + n * 64 + c0;
        short8 b0 = *(const short8*)bp;
        short8 b1 = *(const short8*)(bp + 32);
        aco = __builtin_amdgcn_mfma_f32_16x16x32_bf16(__builtin_bit_cast(short8, v0), b0, aco, 0, 0, 0);
        aco = __builtin_amdgcn_mfma_f32_16x16x32_bf16(__builtin_bit_cast(short8, v1), b1, aco, 0, 0, 0);
    }
    {
        int np = nbh * 16 + r15;
        if (np < 18) {
            float bias = p_b[np];
#pragma unroll
            for (int rr = 0; rr < 4; ++rr) {
                int pix = pg * 16 + g * 4 + rr;
                offs[pix * 18 + np] = aco[rr] + bias;
            }
        }
    }
    __syncthreads();

    // ---- phase 2: bilinear geometry per (pixel, tap) ----
    for (int t = tid; t < 576; t += 512) {
        int p = t / 9;
        int n = t - p * 9;
        float ox = offs[p * 18 + n];
        float oy = offs[p * 18 + 9 + n];
        float px = ox + (float)(i + 1) + (float)(n / 3 - 1);
        float py = oy + (float)(j0 + p + 1) + (float)(n % 3 - 1);
        float fx = floorf(px), fy = floorf(py);
        float qlx = fminf(fmaxf(fx, 0.f), 129.f);
        float qrx = fminf(fmaxf(fx + 1.f, 0.f), 129.f);
        float qly = fminf(fmaxf(fy, 0.f), 129.f);
        float qry = fminf(fmaxf(fy + 1.f, 0.f), 129.f);
        float pxc = fminf(fmaxf(px, 0.f), 129.f);
        float pyc = fminf(fmaxf(py, 0.f), 129.f);
        float ax = 1.f + qlx - pxc;
        float bx = 1.f - qrx + pxc;
        float ay = 1.f + qly - pyc;
        float by = 1.f - qry + pyc;
        int rlx = (int)qlx - 1, rrx = (int)qrx - 1;
        int rly = (int)qly - 1, rry = (int)qry - 1;
        int bb = b * 128;
        bool v0 = ((unsigned)rlx < 128u) && ((unsigned)rly < 128u);
        bool v1 = ((unsigned)rrx < 128u) && ((unsigned)rry < 128u);
        bool v2 = ((unsigned)rlx < 128u) && ((unsigned)rry < 128u);
        bool v3 = ((unsigned)rrx < 128u) && ((unsigned)rly < 128u);
        igeom[(n * 4 + 0) * 64 + p] = v0 ? (((bb + rlx) * 128 + rly) << 6) : 0;
        wgeom[(n * 4 + 0) * 64 + p] = v0 ? ax * ay : 0.f;
        igeom[(n * 4 + 1) * 64 + p] = v1 ? (((bb + rrx) * 128 + rry) << 6) : 0;
        wgeom[(n * 4 + 1) * 64 + p] = v1 ? bx * by : 0.f;
        igeom[(n * 4 + 2) * 64 + p] = v2 ? (((bb + rlx) * 128 + rry) << 6) : 0;
        wgeom[(n * 4 + 2) * 64 + p] = v2 ? ax * by : 0.f;
        igeom[(n * 4 + 3) * 64 + p] = v3 ? (((bb + rrx) * 128 + rly) << 6) : 0;
        wgeom[(n * 4 + 3) * 64 + p] = v3 ? bx * ay : 0.f;
    }
    __syncthreads();

    // ---- phase 3: main conv — branch-free weighted gathers, geometry prefetch ----
    f32x4 acc0 = (f32x4)0.f, acc1 = (f32x4)0.f;

    int baseA[4];
    float wA[4];
#pragma unroll
    for (int k = 0; k < 4; ++k) {
        baseA[k] = igeom[(0 * 4 + k) * 64 + pl];
        wA[k] = wgeom[(0 * 4 + k) * 64 + pl];
    }

    for (int n = 0; n < 9; ++n) {
        // issue gathers for this tap (always, unconditionally)
        ushort8 u0_[4], u1_[4];
#pragma unroll
        for (int k = 0; k < 4; ++k) {
            const unsigned short* ap = x_t + baseA[k] + c0;
            u0_[k] = *(const ushort8*)ap;
            u1_[k] = *(const ushort8*)(ap + 32);
        }
        // prefetch next tap's geometry while gathers are in flight
        int baseB[4];
        float wB[4];
        if (n < 8) {
#pragma unroll
            for (int k = 0; k < 4; ++k) {
                baseB[k] = igeom[((n + 1) * 4 + k) * 64 + pl];
                wB[k] = wgeom[((n + 1) * 4 + k) * 64 + pl];
            }
        }
        float wk0 = wA[0], wk1 = wA[1], wk2 = wA[2], wk3 = wA[3];
        float a0[8], a1[8];
#pragma unroll
        for (int e = 0; e < 8; ++e) {
            a0[e] = wk0 * bf2f(u0_[0][e]);
            a1[e] = wk0 * bf2f(u1_[0][e]);
            a0[e] = fmaf(wk1, bf2f(u0_[1][e]), a0[e]);
            a1[e] = fmaf(wk1, bf2f(u1_[1][e]), a1[e]);
            a0[e] = fmaf(wk2, bf2f(u0_[2][e]), a0[e]);
            a1[e] = fmaf(wk2, bf2f(u1_[2][e]), a1[e]);
            a0[e] = fmaf(wk3, bf2f(u0_[3][e]), a0[e]);
            a1[e] = fmaf(wk3, bf2f(u1_[3][e]), a1[e]);
        }
        short8 fa0, fa1;
#pragma unroll
        for (int e = 0; e < 8; ++e) {
            fa0[e] = (short)f2bf(a0[e]);
            fa1[e] = (short)f2bf(a1[e]);
        }
        {
            const unsigned short* bp0 = cwt + (nbh * 32 + r15) * 576 + n * 64 + c0;
            const unsigned short* bp1 = bp0 + 16 * 576;
            short8 b00 = *(const short8*)bp0;
            short8 b01 = *(const short8*)(bp0 + 32);
            short8 b10 = *(const short8*)bp1;
            short8 b11 = *(const short8*)(bp1 + 32);
            acc0 = __builtin_amdgcn_mfma_f32_16x16x32_bf16(fa0, b00, acc0, 0, 0, 0);
            acc0 = __builtin_amdgcn_mfma_f32_16x16x32_bf16(fa1, b01, acc0, 0, 0, 0);
            acc1 = __builtin_amdgcn_mfma_f32_16x16x32_bf16(fa0, b10, acc1, 0, 0, 0);
            acc1 = __builtin_amdgcn_mfma_f32_16x16x32_bf16(fa1, b11, acc1, 0, 0, 0);
        }
#pragma unroll
        for (int k = 0; k < 4; ++k) { baseA[k] = baseB[k]; wA[k] = wB[k]; }
    }
    __syncthreads();  // geom region now reusable as ep

    // ---- epilogue: LDS transpose, coalesced NCHW store ----
#pragma unroll
    for (int nb = 0; nb < 2; ++nb) {
        int o = nbh * 32 + nb * 16 + r15;
        f32x4 a = nb ? acc1 : acc0;
#pragma unroll
        for (int rr = 0; rr < 4; ++rr) {
            int pix = pg * 16 + g * 4 + rr;
            ep[o * 65 + pix] = a[rr];
        }
    }
    __syncthreads();
    for (int t = tid; t < 4096; t += 512) {
        int o = t >> 6;
        int p = t & 63;
        out[(((size_t)(b * 64 + o)) << 14) + (i << 7) + j0 + p] = ep[o * 65 + p] + conv_b[o];
    }
}

extern "C" void kernel_launch(void* const* d_in, const int* in_sizes, int n_in,
                              void* d_out, int out_size, void* d_ws, size_t ws_size,
                              hipStream_t stream) {
    const float* x = (const float*)d_in[0];
    const float* p_w = (const float*)d_in[1];
    const float* p_b = (const float*)d_in[2];
    const float* conv_w = (const float*)d_in[3];
    const float* conv_b = (const float*)d_in[4];
    float* out = (float*)d_out;
    char* ws = (char*)d_ws;

    unsigned short* x_t = (unsigned short*)(ws);
    unsigned short* cwt = (unsigned short*)(ws + CWT_OFF);
    unsigned short* pwt = (unsigned short*)(ws + PWT_OFF);

    k_prep_x<<<512, 256, 0, stream>>>(x, (unsigned int*)x_t);
    k_prep_w<<<216, 256, 0, stream>>>(conv_w, p_w, cwt, pwt);
    k_fused<<<1024, 512, 0, stream>>>(x_t, cwt, pwt, p_b, conv_b, out);
}

// Round 4
// 53.855 us; speedup vs baseline: 2.6091x; 2.6091x over previous
//
#include <hip/hip_runtime.h>
#include <math.h>

// B=4, C=64, H=W=128, OUTC=64, KS=3, taps N=9, K = 9*64 = 576.
// ws layout (bytes):
//   x_t   bf16 [4][128][128][64]       @ 0        (8 MB) NHWC
//   cwtf  bf16 [9][2][4][64][8]        @ 8388608  (72 KB) main-conv B-fragments
//         cwtf[((n*2+h)*4+nb)*512 + lane*8 + e] = conv_w[o=nb*16+(lane&15)][c=h*32+(lane>>4)*8+e][n]
//   pwtf  bf16 [9][2][2][64][8]        @ 8462336  (36 KB) offset-conv B-fragments (rows>=18 zero)
#define CWTF_OFF 8388608
#define PWTF_OFF (CWTF_OFF + 73728)

typedef __attribute__((ext_vector_type(8))) short short8;
typedef __attribute__((ext_vector_type(8))) unsigned short ushort8;
typedef __attribute__((ext_vector_type(4))) float f32x4;

__device__ inline float bf2f(unsigned short u) {
    union { unsigned int i; float f; } c; c.i = ((unsigned int)u) << 16; return c.f;
}
__device__ inline unsigned short f2bf(float f) {
    union { float f; unsigned int i; } c; c.f = f;
    return (unsigned short)((c.i + 0x7FFFu + ((c.i >> 16) & 1u)) >> 16);
}
__device__ inline unsigned short f2h(float f) {
    _Float16 h = (_Float16)f; return __builtin_bit_cast(unsigned short, h);
}
__device__ inline float h2f(unsigned short u) {
    return (float)__builtin_bit_cast(_Float16, u);
}

// ---------------- prep: x NCHW f32 -> NHWC bf16 ----------------
__global__ __launch_bounds__(256) void k_prep_x(const float* __restrict__ x,
                                                unsigned int* __restrict__ x_t_u32) {
    __shared__ float t[64][129];
    int b = blockIdx.x >> 7;
    int i = blockIdx.x & 127;
    for (int idx = threadIdx.x; idx < 64 * 128; idx += 256) {
        int c = idx >> 7, j = idx & 127;
        t[c][j] = x[(((size_t)(b * 64 + c) * 128 + i) << 7) + j];
    }
    __syncthreads();
    unsigned int* dst = x_t_u32 + ((size_t)(b * 128 + i)) * 128 * 32;
    for (int idx2 = threadIdx.x; idx2 < 4096; idx2 += 256) {
        int j = idx2 >> 5, c2 = idx2 & 31;
        unsigned int lo = f2bf(t[2 * c2][j]);
        unsigned int hi = f2bf(t[2 * c2 + 1][j]);
        dst[idx2] = lo | (hi << 16);
    }
}

// ---------------- prep: weights -> MFMA fragment order ----------------
__global__ __launch_bounds__(256) void k_prep_w(const float* __restrict__ conv_w,
                                                const float* __restrict__ p_w,
                                                unsigned short* __restrict__ cwtf,
                                                unsigned short* __restrict__ pwtf) {
    int tid = blockIdx.x * 256 + threadIdx.x;
    if (tid < 36864) {
        int e = tid & 7, lane = (tid >> 3) & 63, nb = (tid >> 9) & 3, h = (tid >> 11) & 1, n = tid >> 12;
        int o = nb * 16 + (lane & 15);
        int c = h * 32 + ((lane >> 4) << 3) + e;
        cwtf[tid] = f2bf(conv_w[(o * 64 + c) * 9 + n]);
    } else if (tid < 36864 + 18432) {
        int t = tid - 36864;
        int e = t & 7, lane = (t >> 3) & 63, nb = (t >> 9) & 1, h = (t >> 10) & 1, n = t >> 11;
        int np = nb * 16 + (lane & 15);
        int c = h * 32 + ((lane >> 4) << 3) + e;
        pwtf[t] = (np < 18) ? f2bf(p_w[(np * 64 + c) * 9 + n]) : (unsigned short)0;
    }
}

// ---------------- fused kernel ----------------
// Block = 64 pixels (b, i, j0..j0+63), 4 waves, wave = 16-pixel group.
// LDS: swizzled x-tile rows [i-3,i+3] x cols [j0-3,j0+67], all scattered reads from LDS.
// MFMA 16x16x32 bf16: A m=lane&15, k=8*(lane>>4)+e; B n=lane&15 same k; D n=lane&15, m=4*(lane>>4)+reg.
#define TROWS 7
#define TCOLS 71
#define TRECS (TROWS * TCOLS)      // 497 records of 128 B
#define TILE_B (TRECS * 128)       // 63616 B
#define OFF_OFFS TILE_B            // 4608 B  [64][18] f32
#define OFF_GEOM (TILE_B + 4608)   // 9216 B  [9][4][64] packed u32
#define OFF_FLAG (TILE_B + 4608 + 9216)

__global__ __launch_bounds__(256) void k_fused(const unsigned short* __restrict__ x_t,
                                               const unsigned short* __restrict__ cwtf,
                                               const unsigned short* __restrict__ pwtf,
                                               const float* __restrict__ p_b,
                                               const float* __restrict__ conv_b,
                                               float* __restrict__ out) {
    __shared__ __align__(16) unsigned char S[TILE_B + 4608 + 9216 + 16];
    unsigned char* tile = S;
    float* offs = (float*)(S + OFF_OFFS);
    unsigned int* geom = (unsigned int*)(S + OFF_GEOM);
    int* flagp = (int*)(S + OFF_FLAG);
    float* ep = (float*)S;  // epilogue overlays tile

    int bid = blockIdx.x;
    int b = bid >> 8;
    int i = (bid >> 1) & 127;
    int j0 = (bid & 1) << 6;
    int ib = i - 3, jb = j0 - 3;

    int tid = threadIdx.x;
    int wv = tid >> 6;
    int lane = tid & 63;
    int r15 = lane & 15;
    int g = lane >> 4;
    int pl = wv * 16 + r15;  // this lane's A-row pixel

    if (tid == 0) *flagp = 0;

    // ---- stage swizzled x-tile (coalesced global, swizzled LDS) ----
    for (int u = tid; u < TRECS * 8; u += 256) {
        int trow = u / (TCOLS * 8);
        int rem = u - trow * (TCOLS * 8);
        int tcol = rem >> 3, chunk = rem & 7;
        int gr = ib + trow, gc = jb + tcol;
        bool v = ((unsigned)gr < 128u) && ((unsigned)gc < 128u);
        int grc = v ? gr : 0, gcc = v ? gc : 0;
        ushort8 val = *(const ushort8*)(x_t + (((size_t)((b * 128 + grc) * 128 + gcc)) << 6) + (chunk << 3));
        if (!v) val = (ushort8)(unsigned short)0;
        int rec = u >> 3;
        *(ushort8*)(tile + rec * 128 + ((chunk ^ (rec & 7)) << 4)) = val;
    }
    __syncthreads();

    // ---- phase 1: offset conv — A from LDS tile, B coalesced from pwtf ----
    f32x4 aco0 = (f32x4)0.f, aco1 = (f32x4)0.f;
    for (int n = 0; n < 9; ++n) {
        int du = n / 3 - 1, dv = n % 3 - 1;
        int trec = (du + 3) * TCOLS + (pl + dv + 3);
        int xb = trec & 7;
        short8 a0 = *(const short8*)(tile + trec * 128 + ((g ^ xb) << 4));
        short8 a1 = *(const short8*)(tile + trec * 128 + (((g + 4) ^ xb) << 4));
        const unsigned short* pb0 = pwtf + (((n * 2 + 0) * 2) << 9) + (lane << 3);
        const unsigned short* pb1 = pwtf + (((n * 2 + 1) * 2) << 9) + (lane << 3);
        short8 b00 = *(const short8*)pb0;            // h=0, nb=0
        short8 b01 = *(const short8*)(pb0 + 512);    // h=0, nb=1
        short8 b10 = *(const short8*)pb1;            // h=1, nb=0
        short8 b11 = *(const short8*)(pb1 + 512);    // h=1, nb=1
        aco0 = __builtin_amdgcn_mfma_f32_16x16x32_bf16(a0, b00, aco0, 0, 0, 0);
        aco1 = __builtin_amdgcn_mfma_f32_16x16x32_bf16(a0, b01, aco1, 0, 0, 0);
        aco0 = __builtin_amdgcn_mfma_f32_16x16x32_bf16(a1, b10, aco0, 0, 0, 0);
        aco1 = __builtin_amdgcn_mfma_f32_16x16x32_bf16(a1, b11, aco1, 0, 0, 0);
    }
#pragma unroll
    for (int nb = 0; nb < 2; ++nb) {
        int np = nb * 16 + r15;
        if (np < 18) {
            float bias = p_b[np];
            f32x4 a = nb ? aco1 : aco0;
#pragma unroll
            for (int rr = 0; rr < 4; ++rr) {
                int pix = wv * 16 + g * 4 + rr;
                offs[pix * 18 + np] = a[rr] + bias;
            }
        }
    }
    __syncthreads();

    // ---- phase 2: bilinear geometry, packed (validbit|rx|ry|f16 w) ----
    for (int t = tid; t < 576; t += 256) {
        int p = t / 9;
        int n = t - p * 9;
        float ox = offs[p * 18 + n];
        float oy = offs[p * 18 + 9 + n];
        float px = ox + (float)(i + 1) + (float)(n / 3 - 1);
        float py = oy + (float)(j0 + p + 1) + (float)(n % 3 - 1);
        float fx = floorf(px), fy = floorf(py);
        float qlx = fminf(fmaxf(fx, 0.f), 129.f);
        float qrx = fminf(fmaxf(fx + 1.f, 0.f), 129.f);
        float qly = fminf(fmaxf(fy, 0.f), 129.f);
        float qry = fminf(fmaxf(fy + 1.f, 0.f), 129.f);
        float pxc = fminf(fmaxf(px, 0.f), 129.f);
        float pyc = fminf(fmaxf(py, 0.f), 129.f);
        float ax = 1.f + qlx - pxc;
        float bx = 1.f - qrx + pxc;
        float ay = 1.f + qly - pyc;
        float by = 1.f - qry + pyc;
        int rlx = (int)qlx - 1, rrx = (int)qrx - 1;
        int rly = (int)qly - 1, rry = (int)qry - 1;
        bool bad = false;
        unsigned int pk[4];
        int cx[4] = {rlx, rrx, rlx, rrx};
        int cy[4] = {rly, rry, rry, rly};
        float cw[4] = {ax * ay, bx * by, ax * by, bx * ay};
#pragma unroll
        for (int k = 0; k < 4; ++k) {
            bool v = ((unsigned)cx[k] < 128u) && ((unsigned)cy[k] < 128u);
            pk[k] = v ? (0x80000000u | ((unsigned)cx[k] << 23) | ((unsigned)cy[k] << 16) | f2h(cw[k])) : 0u;
            bad = bad || (v && (((unsigned)(cx[k] - ib) >= (unsigned)TROWS) ||
                                ((unsigned)(cy[k] - jb) >= (unsigned)TCOLS)));
        }
#pragma unroll
        for (int k = 0; k < 4; ++k) geom[(n * 4 + k) * 64 + p] = pk[k];
        if (bad) *flagp = 1;
    }
    __syncthreads();

    // ---- phase 3: main conv ----
    f32x4 acc[4];
#pragma unroll
    for (int nb = 0; nb < 4; ++nb) acc[nb] = (f32x4)0.f;
    bool fast = (*flagp == 0);

    for (int n = 0; n < 9; ++n) {
        unsigned int pk[4];
#pragma unroll
        for (int k = 0; k < 4; ++k) pk[k] = geom[(n * 4 + k) * 64 + pl];
        // B fragments: 8 coalesced 1KB loads
        short8 Bf[8];
#pragma unroll
        for (int h = 0; h < 2; ++h)
#pragma unroll
            for (int nb = 0; nb < 4; ++nb)
                Bf[nb * 2 + h] = *(const short8*)(cwtf + ((((n * 2 + h) << 2) + nb) << 9) + (lane << 3));

        float a0[8], a1[8];
#pragma unroll
        for (int e = 0; e < 8; ++e) { a0[e] = 0.f; a1[e] = 0.f; }

        if (fast) {
#pragma unroll
            for (int k = 0; k < 4; ++k) {
                unsigned int p = pk[k];
                int rx = (int)((p >> 23) & 127u), ry = (int)((p >> 16) & 127u);
                int trec = (rx - ib) * TCOLS + (ry - jb);
                if (p == 0u) trec = 0;
                float wk = h2f((unsigned short)(p & 0xFFFFu));
                int xb = trec & 7;
                ushort8 u0 = *(const ushort8*)(tile + trec * 128 + ((g ^ xb) << 4));
                ushort8 u1 = *(const ushort8*)(tile + trec * 128 + (((g + 4) ^ xb) << 4));
#pragma unroll
                for (int e = 0; e < 8; ++e) {
                    a0[e] = fmaf(wk, bf2f(u0[e]), a0[e]);
                    a1[e] = fmaf(wk, bf2f(u1[e]), a1[e]);
                }
            }
        } else {
#pragma unroll
            for (int k = 0; k < 4; ++k) {
                unsigned int p = pk[k];
                int rx = (int)((p >> 23) & 127u), ry = (int)((p >> 16) & 127u);
                size_t base = (p == 0u) ? 0 : (((size_t)((b * 128 + rx) * 128 + ry)) << 6);
                float wk = h2f((unsigned short)(p & 0xFFFFu));
                ushort8 u0 = *(const ushort8*)(x_t + base + (g << 3));
                ushort8 u1 = *(const ushort8*)(x_t + base + 32 + (g << 3));
#pragma unroll
                for (int e = 0; e < 8; ++e) {
                    a0[e] = fmaf(wk, bf2f(u0[e]), a0[e]);
                    a1[e] = fmaf(wk, bf2f(u1[e]), a1[e]);
                }
            }
        }
        short8 fa0, fa1;
#pragma unroll
        for (int e = 0; e < 8; ++e) {
            fa0[e] = (short)f2bf(a0[e]);
            fa1[e] = (short)f2bf(a1[e]);
        }
#pragma unroll
        for (int nb = 0; nb < 4; ++nb) {
            acc[nb] = __builtin_amdgcn_mfma_f32_16x16x32_bf16(fa0, Bf[nb * 2 + 0], acc[nb], 0, 0, 0);
            acc[nb] = __builtin_amdgcn_mfma_f32_16x16x32_bf16(fa1, Bf[nb * 2 + 1], acc[nb], 0, 0, 0);
        }
    }
    __syncthreads();  // tile dead; reuse as ep

    // ---- epilogue: LDS transpose, coalesced NCHW store ----
#pragma unroll
    for (int nb = 0; nb < 4; ++nb) {
        int o = nb * 16 + r15;
#pragma unroll
        for (int rr = 0; rr < 4; ++rr) {
            int pix = wv * 16 + g * 4 + rr;
            ep[o * 65 + pix] = acc[nb][rr];
        }
    }
    __syncthreads();
    for (int t = tid; t < 4096; t += 256) {
        int o = t >> 6;
        int p = t & 63;
        out[(((size_t)(b * 64 + o)) << 14) + (i << 7) + j0 + p] = ep[o * 65 + p] + conv_b[o];
    }
}

extern "C" void kernel_launch(void* const* d_in, const int* in_sizes, int n_in,
                              void* d_out, int out_size, void* d_ws, size_t ws_size,
                              hipStream_t stream) {
    const float* x = (const float*)d_in[0];
    const float* p_w = (const float*)d_in[1];
    const float* p_b = (const float*)d_in[2];
    const float* conv_w = (const float*)d_in[3];
    const float* conv_b = (const float*)d_in[4];
    float* out = (float*)d_out;
    char* ws = (char*)d_ws;

    unsigned short* x_t = (unsigned short*)(ws);
    unsigned short* cwtf = (unsigned short*)(ws + CWTF_OFF);
    unsigned short* pwtf = (unsigned short*)(ws + PWTF_OFF);

    k_prep_x<<<512, 256, 0, stream>>>(x, (unsigned int*)x_t);
    k_prep_w<<<216, 256, 0, stream>>>(conv_w, p_w, cwtf, pwtf);
    k_fused<<<1024, 256, 0, stream>>>(x_t, cwtf, pwtf, p_b, conv_b, out);
}

// Round 6
// 42.704 us; speedup vs baseline: 3.2903x; 1.2611x over previous
//
#include <hip/hip_runtime.h>
#include <math.h>

// B=4, C=64, H=W=128, OUTC=64, KS=3, taps N=9, K = 9*64 = 576. All fp16 data, f32 accum.
// ws layout (bytes):
//   x_t   fp16 [4][128][128][64]       @ 0        (8 MB) NHWC
//   cwtf  fp16 [9][2][4][64][8]        @ 8388608  (72 KB) main-conv B-fragments
//         cwtf[((n*2+h)*4+nb)*512 + lane*8 + e] = conv_w[o=nb*16+(lane&15)][c=h*32+(lane>>4)*8+e][n]
//   pwtf  fp16 [9][2][2][64][8]        @ 8462336  (36 KB) offset-conv B-fragments (rows>=18 zero)
#define CWTF_OFF 8388608
#define PWTF_OFF (CWTF_OFF + 73728)

typedef __attribute__((ext_vector_type(8))) _Float16 half8;
typedef __attribute__((ext_vector_type(8))) unsigned short ushort8;
typedef __attribute__((ext_vector_type(4))) float f32x4;

__device__ inline unsigned short f2h(float f) {
    _Float16 h = (_Float16)f; return __builtin_bit_cast(unsigned short, h);
}

// ---------------- prep: x NCHW f32 -> NHWC fp16, + weights -> fragment order ----------------
__global__ __launch_bounds__(256) void k_prep(const float* __restrict__ x,
                                              unsigned int* __restrict__ x_t_u32,
                                              const float* __restrict__ conv_w,
                                              const float* __restrict__ p_w,
                                              unsigned short* __restrict__ cwtf,
                                              unsigned short* __restrict__ pwtf) {
    if (blockIdx.x < 512) {
        __shared__ float t[64][129];
        int b = blockIdx.x >> 7;
        int i = blockIdx.x & 127;
        for (int idx = threadIdx.x; idx < 64 * 128; idx += 256) {
            int c = idx >> 7, j = idx & 127;
            t[c][j] = x[(((size_t)(b * 64 + c) * 128 + i) << 7) + j];
        }
        __syncthreads();
        unsigned int* dst = x_t_u32 + ((size_t)(b * 128 + i)) * 128 * 32;
        for (int idx2 = threadIdx.x; idx2 < 4096; idx2 += 256) {
            int j = idx2 >> 5, c2 = idx2 & 31;
            unsigned int lo = f2h(t[2 * c2][j]);
            unsigned int hi = f2h(t[2 * c2 + 1][j]);
            dst[idx2] = lo | (hi << 16);
        }
    } else {
        int tid = (blockIdx.x - 512) * 256 + threadIdx.x;
        if (tid < 36864) {
            int e = tid & 7, lane = (tid >> 3) & 63, nb = (tid >> 9) & 3, h = (tid >> 11) & 1, n = tid >> 12;
            int o = nb * 16 + (lane & 15);
            int c = h * 32 + ((lane >> 4) << 3) + e;
            cwtf[tid] = f2h(conv_w[(o * 64 + c) * 9 + n]);
        } else if (tid < 36864 + 18432) {
            int t2 = tid - 36864;
            int e = t2 & 7, lane = (t2 >> 3) & 63, nb = (t2 >> 9) & 1, h = (t2 >> 10) & 1, n = t2 >> 11;
            int np = nb * 16 + (lane & 15);
            int c = h * 32 + ((lane >> 4) << 3) + e;
            pwtf[t2] = (np < 18) ? f2h(p_w[(np * 64 + c) * 9 + n]) : (unsigned short)0;
        }
    }
}

// ---------------- fused kernel ----------------
// Block = 64 pixels (b, i, j0..j0+63), 8 waves (512 thr): wave wv = (pg = wv&3, h = wv>>2).
// Wave (pg,h) handles pixel group pg*16.. and channel half h*32..; MFMA k-halves are
// reduced across h via LDS (offs for phase 1, ep for phase 3).
// MFMA 16x16x32 f16: A m=lane&15, k=8*(lane>>4)+e; B n=lane&15 same k; D n=lane&15, m=4*(lane>>4)+reg.
#define TROWS 7
#define TCOLS 71
#define TRECS (TROWS * TCOLS)      // 497 records of 128 B (64 ch fp16)
#define TILE_B (TRECS * 128)       // 63616 B
#define OFF_OFFS TILE_B            // 4608 B  [64][18] f32
#define OFF_GEOM (TILE_B + 4608)   // 9216 B  [9][4][64] packed u32
#define OFF_FLAG (TILE_B + 4608 + 9216)

__global__ __launch_bounds__(512, 2) void k_fused(const unsigned short* __restrict__ x_t,
                                                  const unsigned short* __restrict__ cwtf,
                                                  const unsigned short* __restrict__ pwtf,
                                                  const float* __restrict__ p_b,
                                                  const float* __restrict__ conv_b,
                                                  float* __restrict__ out) {
    __shared__ __align__(16) unsigned char S[TILE_B + 4608 + 9216 + 16];
    unsigned char* tile = S;
    float* offs = (float*)(S + OFF_OFFS);
    unsigned int* geom = (unsigned int*)(S + OFF_GEOM);
    int* flagp = (int*)(S + OFF_FLAG);
    float* ep = (float*)S;  // epilogue overlays tile

    int bid = blockIdx.x;
    int b = bid >> 8;
    int i = (bid >> 1) & 127;
    int j0 = (bid & 1) << 6;
    int ib = i - 3, jb = j0 - 3;

    int tid = threadIdx.x;
    int wv = tid >> 6;
    int lane = tid & 63;
    int r15 = lane & 15;
    int g = lane >> 4;
    int pg = wv & 3;
    int h = wv >> 2;
    int pl = pg * 16 + r15;      // this lane's A-row pixel
    int cs = g + (h << 2);       // chunk slot: channels cs*8..cs*8+7

    if (tid == 0) *flagp = 0;

    // ---- stage swizzled x-tile (coalesced global, swizzled LDS) ----
    for (int u = tid; u < TRECS * 8; u += 512) {
        int trow = u / (TCOLS * 8);
        int rem = u - trow * (TCOLS * 8);
        int tcol = rem >> 3, chunk = rem & 7;
        int gr = ib + trow, gc = jb + tcol;
        bool v = ((unsigned)gr < 128u) && ((unsigned)gc < 128u);
        int grc = v ? gr : 0, gcc = v ? gc : 0;
        ushort8 val = *(const ushort8*)(x_t + (((size_t)((b * 128 + grc) * 128 + gcc)) << 6) + (chunk << 3));
        if (!v) val = (ushort8)(unsigned short)0;
        int rec = u >> 3;
        *(ushort8*)(tile + rec * 128 + ((chunk ^ (rec & 7)) << 4)) = val;
    }
    __syncthreads();

    // ---- phase 1: offset conv — wave supplies its channel-half's k-block ----
    f32x4 aco0 = (f32x4)0.f, aco1 = (f32x4)0.f;
    for (int n = 0; n < 9; ++n) {
        int du = n / 3 - 1, dv = n % 3 - 1;
        int trec = (du + 3) * TCOLS + (pl + dv + 3);
        int xb = trec & 7;
        half8 a = *(const half8*)(tile + trec * 128 + ((cs ^ xb) << 4));
        const unsigned short* pb = pwtf + (((n * 2 + h) * 2) << 9) + (lane << 3);
        half8 b0 = *(const half8*)pb;
        half8 b1 = *(const half8*)(pb + 512);
        aco0 = __builtin_amdgcn_mfma_f32_16x16x32_f16(a, b0, aco0, 0, 0, 0);
        aco1 = __builtin_amdgcn_mfma_f32_16x16x32_f16(a, b1, aco1, 0, 0, 0);
    }
    // cross-h reduction of offsets: h=0 writes (+bias), h=1 adds
#pragma unroll
    for (int hh = 0; hh < 2; ++hh) {
        if (h == hh) {
#pragma unroll
            for (int nb = 0; nb < 2; ++nb) {
                int np = nb * 16 + r15;
                if (np < 18) {
                    f32x4 a = nb ? aco1 : aco0;
#pragma unroll
                    for (int rr = 0; rr < 4; ++rr) {
                        int pix = pg * 16 + g * 4 + rr;
                        if (hh == 0)
                            offs[pix * 18 + np] = a[rr] + p_b[np];
                        else
                            offs[pix * 18 + np] += a[rr];
                    }
                }
            }
        }
        __syncthreads();
    }

    // ---- phase 2: bilinear geometry, packed (validbit|rx|ry|f16 w) ----
    for (int t = tid; t < 576; t += 512) {
        int p = t / 9;
        int n = t - p * 9;
        float ox = offs[p * 18 + n];
        float oy = offs[p * 18 + 9 + n];
        float px = ox + (float)(i + 1) + (float)(n / 3 - 1);
        float py = oy + (float)(j0 + p + 1) + (float)(n % 3 - 1);
        float fx = floorf(px), fy = floorf(py);
        float qlx = fminf(fmaxf(fx, 0.f), 129.f);
        float qrx = fminf(fmaxf(fx + 1.f, 0.f), 129.f);
        float qly = fminf(fmaxf(fy, 0.f), 129.f);
        float qry = fminf(fmaxf(fy + 1.f, 0.f), 129.f);
        float pxc = fminf(fmaxf(px, 0.f), 129.f);
        float pyc = fminf(fmaxf(py, 0.f), 129.f);
        float ax = 1.f + qlx - pxc;
        float bx = 1.f - qrx + pxc;
        float ay = 1.f + qly - pyc;
        float by = 1.f - qry + pyc;
        int rlx = (int)qlx - 1, rrx = (int)qrx - 1;
        int rly = (int)qly - 1, rry = (int)qry - 1;
        bool bad = false;
        unsigned int pk[4];
        int cx[4] = {rlx, rrx, rlx, rrx};
        int cy[4] = {rly, rry, rry, rly};
        float cw[4] = {ax * ay, bx * by, ax * by, bx * ay};
#pragma unroll
        for (int k = 0; k < 4; ++k) {
            bool v = ((unsigned)cx[k] < 128u) && ((unsigned)cy[k] < 128u);
            pk[k] = v ? (0x80000000u | ((unsigned)cx[k] << 23) | ((unsigned)cy[k] << 16) | f2h(cw[k])) : 0u;
            bad = bad || (v && (((unsigned)(cx[k] - ib) >= (unsigned)TROWS) ||
                                ((unsigned)(cy[k] - jb) >= (unsigned)TCOLS)));
        }
#pragma unroll
        for (int k = 0; k < 4; ++k) geom[(n * 4 + k) * 64 + p] = pk[k];
        if (bad) *flagp = 1;
    }
    __syncthreads();

    // ---- phase 3: main conv — fp16 packed bilinear, wave handles its k-half ----
    f32x4 acc[4];
#pragma unroll
    for (int nb = 0; nb < 4; ++nb) acc[nb] = (f32x4)0.f;
    bool fast = (*flagp == 0);

    for (int n = 0; n < 9; ++n) {
        unsigned int pk[4];
#pragma unroll
        for (int k = 0; k < 4; ++k) pk[k] = geom[(n * 4 + k) * 64 + pl];
        half8 Bf[4];
#pragma unroll
        for (int nb = 0; nb < 4; ++nb)
            Bf[nb] = *(const half8*)(cwtf + ((((n * 2 + h) << 2) + nb) << 9) + (lane << 3));

        half8 av = (half8)(_Float16)0;
        if (fast) {
#pragma unroll
            for (int k = 0; k < 4; ++k) {
                unsigned int p = pk[k];
                int rx = (int)((p >> 23) & 127u), ry = (int)((p >> 16) & 127u);
                int trec = (rx - ib) * TCOLS + (ry - jb);
                if (p == 0u) trec = 0;
                _Float16 wk = __builtin_bit_cast(_Float16, (unsigned short)(p & 0xFFFFu));
                int xb = trec & 7;
                half8 u = *(const half8*)(tile + trec * 128 + ((cs ^ xb) << 4));
                av += u * wk;   // 4x v_pk_fma_f16
            }
        } else {
#pragma unroll
            for (int k = 0; k < 4; ++k) {
                unsigned int p = pk[k];
                int rx = (int)((p >> 23) & 127u), ry = (int)((p >> 16) & 127u);
                size_t base = (p == 0u) ? 0 : (((size_t)((b * 128 + rx) * 128 + ry)) << 6);
                _Float16 wk = __builtin_bit_cast(_Float16, (unsigned short)(p & 0xFFFFu));
                half8 u = *(const half8*)(x_t + base + (cs << 3));
                av += u * wk;
            }
        }
#pragma unroll
        for (int nb = 0; nb < 4; ++nb)
            acc[nb] = __builtin_amdgcn_mfma_f32_16x16x32_f16(av, Bf[nb], acc[nb], 0, 0, 0);
    }
    __syncthreads();  // tile dead; reuse as ep

    // ---- epilogue: cross-h reduction + LDS transpose + coalesced NCHW store ----
#pragma unroll
    for (int hh = 0; hh < 2; ++hh) {
        if (h == hh) {
#pragma unroll
            for (int nb = 0; nb < 4; ++nb) {
                int o = nb * 16 + r15;
#pragma unroll
                for (int rr = 0; rr < 4; ++rr) {
                    int pix = pg * 16 + g * 4 + rr;
                    if (hh == 0)
                        ep[o * 65 + pix] = acc[nb][rr];
                    else
                        ep[o * 65 + pix] += acc[nb][rr];
                }
            }
        }
        __syncthreads();
    }
    for (int t = tid; t < 4096; t += 512) {
        int o = t >> 6;
        int p = t & 63;
        out[(((size_t)(b * 64 + o)) << 14) + (i << 7) + j0 + p] = ep[o * 65 + p] + conv_b[o];
    }
}

extern "C" void kernel_launch(void* const* d_in, const int* in_sizes, int n_in,
                              void* d_out, int out_size, void* d_ws, size_t ws_size,
                              hipStream_t stream) {
    const float* x = (const float*)d_in[0];
    const float* p_w = (const float*)d_in[1];
    const float* p_b = (const float*)d_in[2];
    const float* conv_w = (const float*)d_in[3];
    const float* conv_b = (const float*)d_in[4];
    float* out = (float*)d_out;
    char* ws = (char*)d_ws;

    unsigned short* x_t = (unsigned short*)(ws);
    unsigned short* cwtf = (unsigned short*)(ws + CWTF_OFF);
    unsigned short* pwtf = (unsigned short*)(ws + PWTF_OFF);

    k_prep<<<728, 256, 0, stream>>>(x, (unsigned int*)x_t, conv_w, p_w, cwtf, pwtf);
    k_fused<<<1024, 512, 0, stream>>>(x_t, cwtf, pwtf, p_b, conv_b, out);
}